// Round 4
// baseline (1581.820 us; speedup 1.0000x reference)
//
#include <hip/hip_runtime.h>
#include <hip/hip_bf16.h>
#include <stdint.h>
#include <stddef.h>

// ---------------------------------------------------------------------------
// MixtralAttention on MI355X (gfx950).
// fp32 in/out, bf16 MFMA compute. B=2,S=2048,H=4096,NH=32,NKV=8,D=128
// ws (80 MB): qkv[4096][6144] bf16 (48MB) | wT (32MB, reused; VT aliases tail)
// ---------------------------------------------------------------------------

typedef short short8  __attribute__((ext_vector_type(8)));
typedef short short4v __attribute__((ext_vector_type(4)));
typedef float f32x4   __attribute__((ext_vector_type(4)));

__device__ __forceinline__ short f2bf(float f) {
    union { float f; uint32_t u; } v;
    v.f = f;
    uint32_t u = v.u;
    uint32_t r = (u + 0x7FFFu + ((u >> 16) & 1u)) >> 16;  // RNE
    return (short)(uint16_t)r;
}
__device__ __forceinline__ uint32_t pk2(float x, float y) {
    float2 t; t.x = x; t.y = y;
    __hip_bfloat162 h = __float22bfloat162_rn(t);
    union { __hip_bfloat162 h2; uint32_t u; } c; c.h2 = h; return c.u;
}
__device__ __forceinline__ short8 ldcvt8(const float* p) {
    float4 a = *(const float4*)p;
    float4 b = *(const float4*)(p + 4);
    union { short8 s; uint32_t u[4]; } r;
    r.u[0] = pk2(a.x, a.y); r.u[1] = pk2(a.z, a.w);
    r.u[2] = pk2(b.x, b.y); r.u[3] = pk2(b.z, b.w);
    return r.s;
}
__device__ __forceinline__ void st_out(short* p, float v) { *p = f2bf(v); }
__device__ __forceinline__ void st_out(float* p, float v) { *p = v; }

#define GLDS16(g, l) __builtin_amdgcn_global_load_lds( \
    (const __attribute__((address_space(1))) void*)(g), \
    (__attribute__((address_space(3))) void*)(l), 16, 0, 0)

// ---------------------------------------------------------------------------
// Tiled transpose + fp32->bf16: in[R][ldin] (slice width Cs) -> out[Cs][R]
// ---------------------------------------------------------------------------
__global__ __launch_bounds__(256)
void transpose_cvt(const float* __restrict__ in, int ldin,
                   short* __restrict__ out, int R, int Cs)
{
    __shared__ short tile[64][72];
    const int bc = blockIdx.x * 64;
    const int br = blockIdx.y * 64;
    const int tid = threadIdx.x;
    const int r  = tid >> 2;
    const int c0 = (tid & 3) * 16;

    const float* src = in + (size_t)(br + r) * ldin + bc + c0;
#pragma unroll
    for (int i = 0; i < 4; i++) {
        float4 v = *(const float4*)(src + 4 * i);
        tile[c0 + 4 * i + 0][r] = f2bf(v.x);
        tile[c0 + 4 * i + 1][r] = f2bf(v.y);
        tile[c0 + 4 * i + 2][r] = f2bf(v.z);
        tile[c0 + 4 * i + 3][r] = f2bf(v.w);
    }
    __syncthreads();

    short* dst = out + (size_t)(bc + r) * R + br + c0;
    *(short8*)(dst)     = *(const short8*)(&tile[r][c0]);
    *(short8*)(dst + 8) = *(const short8*)(&tile[r][c0 + 8]);
}

// ---------------------------------------------------------------------------
// bf16 transpose of V: qkv v-slot [2048 tok][128 d] (ld 6144) -> VT[b][hk][128][2048]
// ---------------------------------------------------------------------------
__global__ __launch_bounds__(256)
void transpose_v(const short* __restrict__ qkv, short* __restrict__ VT)
{
    __shared__ short tile[64][72];
    const int bhk = blockIdx.z;
    const int b = bhk >> 3, hk = bhk & 7;
    const int db = blockIdx.x * 64;   // d base
    const int tb = blockIdx.y * 64;   // token base
    const int tid = threadIdx.x;
    const int r  = tid >> 2;          // 0..63
    const int c0 = (tid & 3) * 16;

    const short* src = qkv + (size_t)(b * 2048 + tb + r) * 6144 + 5120 + hk * 128 + db;
    short8 v0 = *(const short8*)(src + c0);
    short8 v1 = *(const short8*)(src + c0 + 8);
#pragma unroll
    for (int i = 0; i < 8; i++) { tile[c0 + i][r] = v0[i]; tile[c0 + 8 + i][r] = v1[i]; }
    __syncthreads();

    short* dst = VT + ((size_t)(b * 8 + hk) * 128 + db + r) * 2048 + tb + c0;
    *(short8*)(dst)     = *(const short8*)(&tile[r][c0]);
    *(short8*)(dst + 8) = *(const short8*)(&tile[r][c0 + 8]);
}

// ---------------------------------------------------------------------------
// GEMM staging. LDS tile T[128][64] bf16, unpadded, XOR-swizzled by 16B chunk.
// ---------------------------------------------------------------------------
__device__ __forceinline__ void stage_tile(const float* __restrict__ Ab, size_t lda,
                                           int kb, short* T, int tid)
{
    const int aRow = tid >> 3;
    const int aChk = tid & 7;
#pragma unroll
    for (int j = 0; j < 4; j++) {
        int row = aRow + 32 * j;
        short8 v = ldcvt8(Ab + (size_t)row * lda + kb + aChk * 8);
        *(short8*)(&T[row * 64 + ((aChk ^ (row & 7)) * 8)]) = v;
    }
}
__device__ __forceinline__ void stage_tile(const short* __restrict__ Ab, size_t lda,
                                           int kb, short* T, int tid)
{
    const int lane = tid & 63;
    const int wave = tid >> 6;
    const int sRow = lane >> 3;
    const int sPhy = lane & 7;
    const int logc = sPhy ^ sRow;
#pragma unroll
    for (int j = 0; j < 4; j++) {
        int row = wave * 32 + j * 8 + sRow;
        const short* g = Ab + (size_t)row * lda + kb + logc * 8;
        GLDS16(g, T + (size_t)(wave * 32 + j * 8) * 64);
    }
}

// ---------------------------------------------------------------------------
// GEMM: C[M,N] = A[M,K] @ Bt[N,K]^T. 128x128 tile, BK=64, 4 waves.
// ---------------------------------------------------------------------------
template <typename AT, typename CT>
__global__ __launch_bounds__(256, 2)
void gemm_tn(const AT* __restrict__ A, int lda, const short* __restrict__ Bt,
             CT* __restrict__ C, int ldc, int M, int N, int K)
{
    __shared__ __align__(16) short As[128 * 64];
    __shared__ __align__(16) short Bs[128 * 64];

    const int tid  = threadIdx.x;
    const int lane = tid & 63;
    const int wave = tid >> 6;
    const int l16  = lane & 15;
    const int quad = lane >> 4;
    const int wm   = wave >> 1;
    const int wn   = wave & 1;
    const int mb   = blockIdx.y;
    const int nb   = blockIdx.x;

    const AT*    Ab = A  + (size_t)mb * 128 * lda;
    const short* Bb = Bt + (size_t)nb * 128 * K;

    f32x4 acc[4][4];
#pragma unroll
    for (int i = 0; i < 4; i++)
#pragma unroll
        for (int j = 0; j < 4; j++) acc[i][j] = {0.f, 0.f, 0.f, 0.f};

    for (int kb = 0; kb < K; kb += 64) {
        __syncthreads();
        stage_tile(Ab, (size_t)lda, kb, As, tid);
        stage_tile(Bb, (size_t)K,   kb, Bs, tid);
        __syncthreads();

#pragma unroll
        for (int ks = 0; ks < 2; ks++) {
            short8 af[4], bf[4];
#pragma unroll
            for (int t = 0; t < 4; t++) {
                int ar = wm * 64 + t * 16 + l16;
                int br = wn * 64 + t * 16 + l16;
                af[t] = *(const short8*)(&As[ar * 64 + (((ks * 4 + quad) ^ (ar & 7)) * 8)]);
                bf[t] = *(const short8*)(&Bs[br * 64 + (((ks * 4 + quad) ^ (br & 7)) * 8)]);
            }
#pragma unroll
            for (int mt = 0; mt < 4; mt++)
#pragma unroll
                for (int nt = 0; nt < 4; nt++)
                    acc[mt][nt] = __builtin_amdgcn_mfma_f32_16x16x32_bf16(
                        af[mt], bf[nt], acc[mt][nt], 0, 0, 0);
        }
    }

#pragma unroll
    for (int mt = 0; mt < 4; mt++)
#pragma unroll
        for (int nt = 0; nt < 4; nt++)
#pragma unroll
            for (int r = 0; r < 4; r++) {
                int row = mb * 128 + wm * 64 + mt * 16 + quad * 4 + r;
                int col = nb * 128 + wn * 64 + nt * 16 + l16;
                st_out(&C[(size_t)row * ldc + col], acc[mt][nt][r]);
            }
}

// ---------------------------------------------------------------------------
// RoPE (neox) in-place on q (32 heads) and k (8 heads) in bf16 qkv ws.
// ---------------------------------------------------------------------------
__global__ __launch_bounds__(256)
void rope_kernel(const int* __restrict__ positions, short* __restrict__ qkv)
{
    const int tok = blockIdx.x;
    const float fp = (float)positions[tok];
    short* base = qkv + (size_t)tok * 6144;
    const float c0 = 0.14391156516f;  // ln(10000)/64

    for (int i = threadIdx.x; i < 40 * 64; i += 256) {
        int head = i >> 6, d = i & 63;
        int off = (head < 32) ? head * 128 : 4096 + (head - 32) * 128;
        float inv = expf(-(float)d * c0);
        float ang = fp * inv;
        float c = cosf(ang);
        float s = sinf(ang);
        union { uint32_t u; float f; } x1, x2;
        x1.u = ((uint32_t)(uint16_t)base[off + d]) << 16;
        x2.u = ((uint32_t)(uint16_t)base[off + d + 64]) << 16;
        base[off + d]      = f2bf(x1.f * c - x2.f * s);
        base[off + d + 64] = f2bf(x2.f * c + x1.f * s);
    }
}

// ---------------------------------------------------------------------------
// Causal GQA flash attention, barrier-free K-loop.
// S^T = K·Q^T (lane owns one q-row); O^T = V^T·P^T; P via per-wave LDS.
// Output written in-place into the q-slot. Grid 2048, 4 waves x 16 rows.
// ---------------------------------------------------------------------------
__global__ __launch_bounds__(256, 3)
void attn_kernel(short* __restrict__ qkv, const short* __restrict__ VT)
{
    __shared__ __align__(16) short Pl[4][16][72];

    const int blk = blockIdx.x;
    const int qb  = 31 - (blk & 31);      // heavy blocks first
    const int h   = (blk >> 5) & 31;
    const int b   = blk >> 10;
    const int hk  = h >> 2;

    const int tid  = threadIdx.x;
    const int lane = tid & 63;
    const int wave = tid >> 6;
    const int l16  = lane & 15;
    const int quad = lane >> 4;

    const size_t ld = 6144;
    const short* Kb = qkv + (size_t)b * 2048 * ld + 4096 + hk * 128;
    const short* Vb = VT + (size_t)(b * 8 + hk) * 128 * 2048;

    // this lane's q-row; Q frag = B-operand (lane = q-row, d-contiguous)
    const int qrow = qb * 64 + wave * 16 + l16;
    const short* Qp = qkv + (size_t)(b * 2048 + qrow) * ld + h * 128;
    short8 qf[4];
#pragma unroll
    for (int ks = 0; ks < 4; ks++) qf[ks] = *(const short8*)(Qp + ks * 32 + quad * 8);

    f32x4 oacc[8];
#pragma unroll
    for (int g = 0; g < 8; g++) oacc[g] = {0.f, 0.f, 0.f, 0.f};
    float m_i = -1e30f, l_i = 0.f;
    const float scale = 0.08838834764831845f;

    short* pbase = &Pl[wave][l16][0];

    for (int kt = 0; kt <= qb; kt++) {
        const short* Kt = Kb + (size_t)kt * 64 * ld;

        // S^T: D[key][qrow], A = K rows (direct global), B = Q
        f32x4 sacc[4];
#pragma unroll
        for (int g = 0; g < 4; g++) {
            sacc[g] = {0.f, 0.f, 0.f, 0.f};
#pragma unroll
            for (int ks = 0; ks < 4; ks++) {
                short8 kf = *(const short8*)(Kt + (size_t)(g * 16 + l16) * ld + ks * 32 + quad * 8);
                sacc[g] = __builtin_amdgcn_mfma_f32_16x16x32_bf16(kf, qf[ks], sacc[g], 0, 0, 0);
            }
        }

        // scale + causal mask (t > qrow exact for all tiles) — lane owns row l16
        float sv[16];
#pragma unroll
        for (int g = 0; g < 4; g++)
#pragma unroll
            for (int r = 0; r < 4; r++) {
                int t = kt * 64 + g * 16 + quad * 4 + r;
                float x = sacc[g][r] * scale;
                sv[g * 4 + r] = (t > qrow) ? -1e30f : x;
            }

        // online softmax: 15 VALU max + 2 shfl; exp; 2 shfl sum
        float mx = sv[0];
#pragma unroll
        for (int i = 1; i < 16; i++) mx = fmaxf(mx, sv[i]);
        mx = fmaxf(mx, __shfl_xor(mx, 16, 64));
        mx = fmaxf(mx, __shfl_xor(mx, 32, 64));
        float mn = fmaxf(m_i, mx);
        float al = __expf(m_i - mn);
        float rs = 0.f;
#pragma unroll
        for (int i = 0; i < 16; i++) {
            float p = __expf(sv[i] - mn);
            sv[i] = p;
            rs += p;
        }
        rs += __shfl_xor(rs, 16, 64);
        rs += __shfl_xor(rs, 32, 64);
        l_i = l_i * al + rs;
        m_i = mn;
#pragma unroll
        for (int gd = 0; gd < 8; gd++)
#pragma unroll
            for (int r = 0; r < 4; r++) oacc[gd][r] *= al;

        // P^T -> per-wave LDS in PV-A-layout rows (no barrier: same wave)
#pragma unroll
        for (int g = 0; g < 4; g++) {
            *(uint32_t*)(pbase + g * 16 + quad * 4)     = pk2(sv[g * 4 + 0], sv[g * 4 + 1]);
            *(uint32_t*)(pbase + g * 16 + quad * 4 + 2) = pk2(sv[g * 4 + 2], sv[g * 4 + 3]);
        }

        // O^T += V^T · P^T  (A = V^T rows, direct global; B = P from LDS)
#pragma unroll
        for (int ks = 0; ks < 2; ks++) {
            short8 pa = *(const short8*)(pbase + ks * 32 + quad * 8);
#pragma unroll
            for (int gd = 0; gd < 8; gd++) {
                short8 vf = *(const short8*)(Vb + (size_t)(gd * 16 + l16) * 2048 + kt * 64 + ks * 32 + quad * 8);
                oacc[gd] = __builtin_amdgcn_mfma_f32_16x16x32_bf16(vf, pa, oacc[gd], 0, 0, 0);
            }
        }
    }

    // epilogue: O^T[d][m] -> row qrow of q-slot; lane owns its row
    float inv = 1.0f / l_i;
    short* orow = qkv + (size_t)(b * 2048 + qrow) * ld + h * 128;
#pragma unroll
    for (int gd = 0; gd < 8; gd++) {
        union { short4v s; uint32_t u[2]; } w;
        w.u[0] = pk2(oacc[gd][0] * inv, oacc[gd][1] * inv);
        w.u[1] = pk2(oacc[gd][2] * inv, oacc[gd][3] * inv);
        *(short4v*)(orow + gd * 16 + quad * 4) = w.s;
    }
}

// ---------------------------------------------------------------------------
// launcher
// ---------------------------------------------------------------------------
extern "C" void kernel_launch(void* const* d_in, const int* in_sizes, int n_in,
                              void* d_out, int out_size, void* d_ws, size_t ws_size,
                              hipStream_t stream)
{
    const int*   positions = (const int*)d_in[0];
    const float* hidden    = (const float*)d_in[1];  // fp32 [4096, 4096]
    const float* w_qkv     = (const float*)d_in[2];  // fp32 [4096, 6144]
    const float* w_o       = (const float*)d_in[3];  // fp32 [4096, 4096]
    float* out = (float*)d_out;                      // fp32 [4096, 4096]

    short* qkv = (short*)d_ws;                       // bf16 [4096][6144], 48 MB
    short* wT  = qkv + (size_t)4096 * 6144;          // 32 MB transpose buffer
    short* VT  = wT + (size_t)3072 * 4096;           // 8 MB, aliases wT tail

    // 1) QKV projection in two N-chunks of 3072
    for (int c = 0; c < 2; c++) {
        transpose_cvt<<<dim3(48, 64), 256, 0, stream>>>(
            w_qkv + c * 3072, 6144, wT, 4096, 3072);
        gemm_tn<float, short><<<dim3(24, 32), 256, 0, stream>>>(
            hidden, 4096, wT, qkv + c * 3072, 6144, 4096, 3072, 4096);
    }
    // 2) RoPE in place on q,k
    rope_kernel<<<4096, 256, 0, stream>>>(positions, qkv);
    // 3) materialize V^T [b][hk][128][2048]
    transpose_v<<<dim3(2, 32, 16), 256, 0, stream>>>(qkv, VT);
    // 4) causal GQA flash attention (output -> q-slot)
    attn_kernel<<<2048, 256, 0, stream>>>(qkv, VT);
    // 5) output projection: A = q-slot of qkv (lda 6144), B = w_o^T
    transpose_cvt<<<dim3(64, 64), 256, 0, stream>>>(w_o, 4096, wT, 4096, 4096);
    gemm_tn<short, float><<<dim3(32, 32), 256, 0, stream>>>(
        qkv, 6144, wT, out, 4096, 4096, 4096, 4096);
}